// Round 8
// baseline (691.262 us; speedup 1.0000x reference)
//
#include <hip/hip_runtime.h>
#include <math.h>

#define N_NODES 4096
#define F_DIM   128
#define E_EDGES 131072
#define NHEADS  8
#define HD      16
#define C_OUT   64

// ---------------- graph prep ----------------
__global__ void deg_count(const int* __restrict__ col, int* __restrict__ deg) {
  int e = blockIdx.x * blockDim.x + threadIdx.x;
  if (e < E_EDGES) atomicAdd(&deg[col[e]], 1);
}

// exclusive prefix sum of deg[4096] -> offs[4097], plus dinv; 1024 thr x 4
__global__ void scan_kernel(const int* __restrict__ deg, int* __restrict__ offs,
                            float* __restrict__ dinv) {
  __shared__ int part[1024];
  int t = threadIdx.x;
  int v0 = deg[t*4+0], v1 = deg[t*4+1], v2 = deg[t*4+2], v3 = deg[t*4+3];
  dinv[t*4+0] = rsqrtf((float)(v0 + 1));
  dinv[t*4+1] = rsqrtf((float)(v1 + 1));
  dinv[t*4+2] = rsqrtf((float)(v2 + 1));
  dinv[t*4+3] = rsqrtf((float)(v3 + 1));
  int s = v0 + v1 + v2 + v3;
  part[t] = s;
  __syncthreads();
  for (int off = 1; off < 1024; off <<= 1) {
    int x = (t >= off) ? part[t - off] : 0;
    __syncthreads();
    part[t] += x;
    __syncthreads();
  }
  int excl = part[t] - s;
  offs[t*4+0] = excl; excl += v0;
  offs[t*4+1] = excl; excl += v1;
  offs[t*4+2] = excl; excl += v2;
  offs[t*4+3] = excl; excl += v3;
  if (t == 1023) offs[4096] = excl;
}

__global__ void fill_csr(const int* __restrict__ row, const int* __restrict__ col,
                         const int* __restrict__ offs, int* __restrict__ cursor,
                         int* __restrict__ src) {
  int e = blockIdx.x * blockDim.x + threadIdx.x;
  if (e < E_EDGES) {
    int c = col[e];
    int p = atomicAdd(&cursor[c], 1);
    src[offs[c] + p] = row[e];
  }
}

// 8 nodes/block, 32 lanes x float4 per node.
__global__ __launch_bounds__(256) void gcn_agg(const float* __restrict__ t,
                                               const float* __restrict__ dinv,
                                               const int* __restrict__ offs,
                                               const int* __restrict__ src,
                                               const float* __restrict__ bias,
                                               float* __restrict__ out) {
  const int node = blockIdx.x * 8 + (threadIdx.x >> 5);
  const int lane = threadIdx.x & 31;
  const float dc = dinv[node];
  float4 a0 = *(const float4*)&t[node * F_DIM + lane * 4];
  a0.x *= dc; a0.y *= dc; a0.z *= dc; a0.w *= dc;
  float4 a1 = make_float4(0.f, 0.f, 0.f, 0.f);
  int e = offs[node], end = offs[node + 1];
  for (; e + 2 <= end; e += 2) {
    int r0 = src[e], r1 = src[e + 1];
    float w0 = dinv[r0], w1 = dinv[r1];
    const float4 v0 = *(const float4*)&t[r0 * F_DIM + lane * 4];
    const float4 v1 = *(const float4*)&t[r1 * F_DIM + lane * 4];
    a0.x = fmaf(w0, v0.x, a0.x); a0.y = fmaf(w0, v0.y, a0.y);
    a0.z = fmaf(w0, v0.z, a0.z); a0.w = fmaf(w0, v0.w, a0.w);
    a1.x = fmaf(w1, v1.x, a1.x); a1.y = fmaf(w1, v1.y, a1.y);
    a1.z = fmaf(w1, v1.z, a1.z); a1.w = fmaf(w1, v1.w, a1.w);
  }
  if (e < end) {
    int r0 = src[e];
    float w0 = dinv[r0];
    const float4 v0 = *(const float4*)&t[r0 * F_DIM + lane * 4];
    a0.x = fmaf(w0, v0.x, a0.x); a0.y = fmaf(w0, v0.y, a0.y);
    a0.z = fmaf(w0, v0.z, a0.z); a0.w = fmaf(w0, v0.w, a0.w);
  }
  a0.x += a1.x; a0.y += a1.y; a0.z += a1.z; a0.w += a1.w;
  const float4 bb = *(const float4*)&bias[lane * 4];
  float4 r;
  r.x = fmaxf(fmaf(a0.x, dc, bb.x), 0.f);
  r.y = fmaxf(fmaf(a0.y, dc, bb.y), 0.f);
  r.z = fmaxf(fmaf(a0.z, dc, bb.z), 0.f);
  r.w = fmaxf(fmaf(a0.w, dc, bb.w), 0.f);
  *(float4*)&out[node * F_DIM + lane * 4] = r;
}

// ---------------- GEMM: TM x 64 tile, BK=32, 256 threads ----------------
// NT=false: B is [K x ldb] row-major; NT=true: B is [Ntot x K] row-major.
// DUAL: C = epi(A@B + A2@B2 + bias + bias2)
template<int TM, bool NT, bool BIAS, bool RELU, bool DUAL>
__global__ __launch_bounds__(256) void gemm2(const float* __restrict__ A,
                                             const float* __restrict__ B,
                                             const float* __restrict__ bias,
                                             const float* __restrict__ A2,
                                             const float* __restrict__ B2,
                                             const float* __restrict__ bias2,
                                             float* __restrict__ C,
                                             int ldb, int ldc) {
  constexpr int K = 128, BK = 32, TN = 64;
  constexpr int RM = TM * TN / 1024;
  constexpr int LDA = 36;
  constexpr int LDB = TN + 4;
  __shared__ float As[BK * LDA];
  __shared__ float Bs[BK * LDB];
  const int tid = threadIdx.x;
  const int tx = tid & 15;
  const int ty = tid >> 4;
  const int row0 = blockIdx.x * TM;
  const int jg0  = blockIdx.y * TN;

  float acc[RM][4];
  #pragma unroll
  for (int r = 0; r < RM; ++r) { acc[r][0]=0.f; acc[r][1]=0.f; acc[r][2]=0.f; acc[r][3]=0.f; }

  for (int pass = 0; pass < (DUAL ? 2 : 1); ++pass) {
    const float* Ap = (DUAL && pass) ? A2 : A;
    const float* Bp = (DUAL && pass) ? B2 : B;
    for (int kc = 0; kc < K; kc += BK) {
      __syncthreads();
      {
        constexpr int NL = TM * BK / 4;
        for (int idx = tid; idx < NL; idx += 256) {
          int m  = idx >> 3;
          int k4 = idx & 7;
          const float4 g = *(const float4*)&Ap[(row0 + m) * K + kc + k4 * 4];
          As[(k4*4+0)*LDA + m] = g.x;
          As[(k4*4+1)*LDA + m] = g.y;
          As[(k4*4+2)*LDA + m] = g.z;
          As[(k4*4+3)*LDA + m] = g.w;
        }
      }
      if constexpr (NT) {
        constexpr int NL = TN * 8;
        for (int idx = tid; idx < NL; idx += 256) {
          int n  = idx >> 3;
          int k4 = idx & 7;
          const float4 g = *(const float4*)&Bp[(jg0 + n) * K + kc + k4 * 4];
          Bs[(k4*4+0)*LDB + n] = g.x;
          Bs[(k4*4+1)*LDB + n] = g.y;
          Bs[(k4*4+2)*LDB + n] = g.z;
          Bs[(k4*4+3)*LDB + n] = g.w;
        }
      } else {
        constexpr int NL = BK * TN / 4;
        for (int idx = tid; idx < NL; idx += 256) {
          int k  = idx >> 4;
          int n4 = idx & 15;
          *(float4*)&Bs[k * LDB + n4 * 4] =
              *(const float4*)&Bp[(kc + k) * ldb + jg0 + n4 * 4];
        }
      }
      __syncthreads();
      #pragma unroll
      for (int k = 0; k < BK; ++k) {
        const float4 bv = *(const float4*)&Bs[k * LDB + tx * 4];
        #pragma unroll
        for (int r = 0; r < RM; ++r) {
          const float a = As[k * LDA + ty * RM + r];
          acc[r][0] = fmaf(a, bv.x, acc[r][0]);
          acc[r][1] = fmaf(a, bv.y, acc[r][1]);
          acc[r][2] = fmaf(a, bv.z, acc[r][2]);
          acc[r][3] = fmaf(a, bv.w, acc[r][3]);
        }
      }
    }
  }

  #pragma unroll
  for (int r = 0; r < RM; ++r) {
    const int gr = row0 + ty * RM + r;
    const int gc = jg0 + tx * 4;
    float4 v = make_float4(acc[r][0], acc[r][1], acc[r][2], acc[r][3]);
    if constexpr (BIAS) {
      const float4 bb = *(const float4*)&bias[gc];
      v.x += bb.x; v.y += bb.y; v.z += bb.z; v.w += bb.w;
    }
    if constexpr (DUAL) {
      const float4 bb = *(const float4*)&bias2[gc];
      v.x += bb.x; v.y += bb.y; v.z += bb.z; v.w += bb.w;
    }
    if constexpr (RELU) {
      v.x = fmaxf(v.x, 0.f); v.y = fmaxf(v.y, 0.f);
      v.z = fmaxf(v.z, 0.f); v.w = fmaxf(v.w, 0.f);
    }
    *(float4*)&C[gr * ldc + gc] = v;
  }
}

// ---------------- per-head max key norm (for bound-softmax) ----------------
__global__ __launch_bounds__(256) void kmax_kernel(const float* __restrict__ qkv,
                                                   float* __restrict__ kmax) {
  const int h = blockIdx.x;
  float mx = 0.f;
  for (int j = threadIdx.x; j < N_NODES; j += 256) {
    const float4* kp = (const float4*)&qkv[j * 384 + 128 + h * HD];
    const float4 k0 = kp[0], k1 = kp[1], k2 = kp[2], k3 = kp[3];
    float n = k0.x*k0.x + k0.y*k0.y + k0.z*k0.z + k0.w*k0.w;
    n += k1.x*k1.x + k1.y*k1.y + k1.z*k1.z + k1.w*k1.w;
    n += k2.x*k2.x + k2.y*k2.y + k2.z*k2.z + k2.w*k2.w;
    n += k3.x*k3.x + k3.y*k3.y + k3.z*k3.z + k3.w*k3.w;
    mx = fmaxf(mx, n);
  }
  #pragma unroll
  for (int mask = 1; mask <= 32; mask <<= 1)
    mx = fmaxf(mx, __shfl_xor(mx, mask, 64));
  __shared__ float red[4];
  if ((threadIdx.x & 63) == 0) red[threadIdx.x >> 6] = mx;
  __syncthreads();
  if (threadIdx.x == 0) {
    float m = fmaxf(fmaxf(red[0], red[1]), fmaxf(red[2], red[3]));
    kmax[h] = sqrtf(m);
  }
}

// ---------------- flash attention v8: bound-softmax, two-phase chunks -------
// R4's proven-spill-free two-phase structure (QK+exp phase filling s[4][8],
// then separate PV phase) + fixed per-row bound M_r = ||q'_r||*kmax[h]:
// no online max, no accumulator rescale. The fused one-phase form (R6/R7)
// spilled 540 MB regardless of __launch_bounds__; this form compiled to
// VGPR=128 with WRITE_SIZE=2 MB (R4 measured).
__global__ __launch_bounds__(256, 2) void attn_kernel(const float* __restrict__ qkv,
                                                      const float* __restrict__ kmax,
                                                      float* __restrict__ o) {
  constexpr int TQ = 64, TK = 256, LDK = 20;
  __shared__ float Ks[TK * LDK];   // 20480 B
  __shared__ float Vs[TK * LDK];   // 20480 B
  const int h   = blockIdx.y;
  const int rg  = threadIdx.x >> 4;     // 16 groups x 4 rows
  const int sub = threadIdx.x & 15;     // key stride 16
  const int row0 = blockIdx.x * TQ + rg * 4;
  const float km = kmax[h];

  float4 q[4][4];
  float M[4];
  #pragma unroll
  for (int r = 0; r < 4; ++r) {
    const float4* qp = (const float4*)&qkv[(row0 + r) * 384 + h * HD];
    float qn = 0.f;
    #pragma unroll
    for (int c = 0; c < 4; ++c) {
      float4 v = qp[c];
      v.x *= 0.25f; v.y *= 0.25f; v.z *= 0.25f; v.w *= 0.25f;
      q[r][c] = v;
      qn += v.x*v.x + v.y*v.y + v.z*v.z + v.w*v.w;
    }
    M[r] = sqrtf(qn) * km;
  }
  float l[4] = {0.f, 0.f, 0.f, 0.f};
  float4 oa[4][4];
  #pragma unroll
  for (int r = 0; r < 4; ++r)
    #pragma unroll
    for (int c = 0; c < 4; ++c) oa[r][c] = make_float4(0.f, 0.f, 0.f, 0.f);

  for (int kt = 0; kt < N_NODES; kt += TK) {
    __syncthreads();
    for (int fi = threadIdx.x; fi < TK * 4; fi += 256) {
      int r = fi >> 2, c4 = fi & 3;
      *(float4*)&Ks[r * LDK + c4 * 4] =
          *(const float4*)&qkv[(kt + r) * 384 + 128 + h * HD + c4 * 4];
      *(float4*)&Vs[r * LDK + c4 * 4] =
          *(const float4*)&qkv[(kt + r) * 384 + 256 + h * HD + c4 * 4];
    }
    __syncthreads();

    for (int j0 = 0; j0 < TK; j0 += 128) {       // thread keys: j0 + kk*16 + sub
      float s[4][8];                              // exp'd scores [row][kk]
      #pragma unroll
      for (int kk = 0; kk < 8; ++kk) {
        const float4* kp = (const float4*)&Ks[(j0 + kk * 16 + sub) * LDK];
        const float4 k0 = kp[0], k1 = kp[1], k2 = kp[2], k3 = kp[3];
        #pragma unroll
        for (int r = 0; r < 4; ++r) {
          float p0 = fmaf(q[r][0].x,k0.x, fmaf(q[r][0].y,k0.y, fmaf(q[r][0].z,k0.z, q[r][0].w*k0.w)));
          float p1 = fmaf(q[r][1].x,k1.x, fmaf(q[r][1].y,k1.y, fmaf(q[r][1].z,k1.z, q[r][1].w*k1.w)));
          float p2 = fmaf(q[r][2].x,k2.x, fmaf(q[r][2].y,k2.y, fmaf(q[r][2].z,k2.z, q[r][2].w*k2.w)));
          float p3 = fmaf(q[r][3].x,k3.x, fmaf(q[r][3].y,k3.y, fmaf(q[r][3].z,k3.z, q[r][3].w*k3.w)));
          s[r][kk] = __expf(((p0 + p1) + (p2 + p3)) - M[r]);
        }
      }
      #pragma unroll
      for (int r = 0; r < 4; ++r) {
        l[r] += ((s[r][0]+s[r][1]) + (s[r][2]+s[r][3])) +
                ((s[r][4]+s[r][5]) + (s[r][6]+s[r][7]));
      }
      #pragma unroll
      for (int kk = 0; kk < 8; ++kk) {
        const float4* vp = (const float4*)&Vs[(j0 + kk * 16 + sub) * LDK];
        const float4 v0 = vp[0], v1 = vp[1], v2 = vp[2], v3 = vp[3];
        #pragma unroll
        for (int r = 0; r < 4; ++r) {
          const float p = s[r][kk];
          oa[r][0].x = fmaf(p, v0.x, oa[r][0].x); oa[r][0].y = fmaf(p, v0.y, oa[r][0].y);
          oa[r][0].z = fmaf(p, v0.z, oa[r][0].z); oa[r][0].w = fmaf(p, v0.w, oa[r][0].w);
          oa[r][1].x = fmaf(p, v1.x, oa[r][1].x); oa[r][1].y = fmaf(p, v1.y, oa[r][1].y);
          oa[r][1].z = fmaf(p, v1.z, oa[r][1].z); oa[r][1].w = fmaf(p, v1.w, oa[r][1].w);
          oa[r][2].x = fmaf(p, v2.x, oa[r][2].x); oa[r][2].y = fmaf(p, v2.y, oa[r][2].y);
          oa[r][2].z = fmaf(p, v2.z, oa[r][2].z); oa[r][2].w = fmaf(p, v2.w, oa[r][2].w);
          oa[r][3].x = fmaf(p, v3.x, oa[r][3].x); oa[r][3].y = fmaf(p, v3.y, oa[r][3].y);
          oa[r][3].z = fmaf(p, v3.z, oa[r][3].z); oa[r][3].w = fmaf(p, v3.w, oa[r][3].w);
        }
      }
    }
  }

  // plain-add butterfly merge over the 16 sub-lanes (in-wave, no LDS)
  #pragma unroll
  for (int mask = 1; mask <= 8; mask <<= 1) {
    #pragma unroll
    for (int r = 0; r < 4; ++r) {
      l[r] += __shfl_xor(l[r], mask, 64);
      #pragma unroll
      for (int c = 0; c < 4; ++c) {
        oa[r][c].x += __shfl_xor(oa[r][c].x, mask, 64);
        oa[r][c].y += __shfl_xor(oa[r][c].y, mask, 64);
        oa[r][c].z += __shfl_xor(oa[r][c].z, mask, 64);
        oa[r][c].w += __shfl_xor(oa[r][c].w, mask, 64);
      }
    }
  }
  // all 16 sub-lanes hold full sums; lane sub writes row (sub>>2), dims (sub&3)
  {
    const int r = sub >> 2;
    const int g = sub & 3;
    const float invL = 1.f / l[r];
    float4 res = oa[r][g];
    res.x *= invL; res.y *= invL; res.z *= invL; res.w *= invL;
    *(float4*)&o[(row0 + r) * F_DIM + h * HD + g * 4] = res;
  }
}

// ---------------- launcher ----------------
extern "C" void kernel_launch(void* const* d_in, const int* in_sizes, int n_in,
                              void* d_out, int out_size, void* d_ws, size_t ws_size,
                              hipStream_t stream) {
  const float* x   = (const float*)d_in[0];
  const int*   ei  = (const int*)  d_in[1];
  const float* W1  = (const float*)d_in[2];
  const float* b1  = (const float*)d_in[3];
  const float* W2  = (const float*)d_in[4];
  const float* b2  = (const float*)d_in[5];
  const float* W3  = (const float*)d_in[6];
  const float* b3  = (const float*)d_in[7];
  const float* ipw = (const float*)d_in[8];
  const float* ipb = (const float*)d_in[9];
  const float* opw = (const float*)d_in[10];
  const float* opb = (const float*)d_in[11];
  const float* pw  = (const float*)d_in[12];
  const float* pb  = (const float*)d_in[13];
  float* out = (float*)d_out;

  int*   deg    = (int*)d_ws;            // 4096
  int*   cursor = deg + 4096;            // 4096
  int*   offs   = cursor + 4096;         // 4100 (4097 used)
  int*   csrc   = offs + 4100;           // 131072
  float* dinv   = (float*)(csrc + E_EDGES);        // 4096
  float* bufA   = dinv + 4096;           // 524288 (t1/t2, then x_tf)
  float* bufB   = bufA + 524288;         // 524288 (h1/h2)
  float* qkv    = bufB + 524288;         // 1572864
  float* obuf   = qkv + 1572864;         // 524288
  float* kmax   = obuf + 524288;         // 8

  const int* rowp = ei;
  const int* colp = ei + E_EDGES;

  hipMemsetAsync(deg, 0, 8192 * sizeof(int), stream);  // deg + cursor
  deg_count<<<E_EDGES / 256, 256, 0, stream>>>(colp, deg);
  scan_kernel<<<1, 1024, 0, stream>>>(deg, offs, dinv);
  fill_csr<<<E_EDGES / 256, 256, 0, stream>>>(rowp, colp, offs, cursor, csrc);

  // GCN branch
  gemm2<32, false, false, false, false><<<dim3(128, 2), 256, 0, stream>>>(
      x, W1, nullptr, nullptr, nullptr, nullptr, bufA, 128, 128);
  gcn_agg<<<N_NODES / 8, 256, 0, stream>>>(bufA, dinv, offs, csrc, b1, bufB);
  gemm2<32, false, false, false, false><<<dim3(128, 2), 256, 0, stream>>>(
      bufB, W2, nullptr, nullptr, nullptr, nullptr, bufA, 128, 128);
  gcn_agg<<<N_NODES / 8, 256, 0, stream>>>(bufA, dinv, offs, csrc, b2, bufB);
  // bufB = h2 (kept for final dual GEMM)

  // transformer branch
  gemm2<32, true, true, false, false><<<dim3(128, 6), 256, 0, stream>>>(
      x, ipw, ipb, nullptr, nullptr, nullptr, qkv, 128, 384);
  kmax_kernel<<<NHEADS, 256, 0, stream>>>(qkv, kmax);
  attn_kernel<<<dim3(64, NHEADS), 256, 0, stream>>>(qkv, kmax, obuf);
  gemm2<32, true, true, false, false><<<dim3(128, 2), 256, 0, stream>>>(
      obuf, opw, opb, nullptr, nullptr, nullptr, bufA, 128, 128);  // bufA = x_tf

  // out = relu(h2@W3 + b3 + x_tf@pw + pb)
  gemm2<16, false, true, true, true><<<dim3(256, 1), 256, 0, stream>>>(
      bufB, W3, b3, bufA, pw, pb, out, 64, C_OUT);
}

// Round 9
// 335.100 us; speedup vs baseline: 2.0629x; 2.0629x over previous
//
#include <hip/hip_runtime.h>
#include <math.h>

#define N_NODES 4096
#define F_DIM   128
#define E_EDGES 131072
#define NHEADS  8
#define HD      16
#define C_OUT   64

// ---------------- graph prep ----------------
__global__ void deg_count(const int* __restrict__ col, int* __restrict__ deg) {
  int e = blockIdx.x * blockDim.x + threadIdx.x;
  if (e < E_EDGES) atomicAdd(&deg[col[e]], 1);
}

// exclusive prefix sum of deg[4096] -> offs[4097], plus dinv; 1024 thr x 4
__global__ void scan_kernel(const int* __restrict__ deg, int* __restrict__ offs,
                            float* __restrict__ dinv) {
  __shared__ int part[1024];
  int t = threadIdx.x;
  int v0 = deg[t*4+0], v1 = deg[t*4+1], v2 = deg[t*4+2], v3 = deg[t*4+3];
  dinv[t*4+0] = rsqrtf((float)(v0 + 1));
  dinv[t*4+1] = rsqrtf((float)(v1 + 1));
  dinv[t*4+2] = rsqrtf((float)(v2 + 1));
  dinv[t*4+3] = rsqrtf((float)(v3 + 1));
  int s = v0 + v1 + v2 + v3;
  part[t] = s;
  __syncthreads();
  for (int off = 1; off < 1024; off <<= 1) {
    int x = (t >= off) ? part[t - off] : 0;
    __syncthreads();
    part[t] += x;
    __syncthreads();
  }
  int excl = part[t] - s;
  offs[t*4+0] = excl; excl += v0;
  offs[t*4+1] = excl; excl += v1;
  offs[t*4+2] = excl; excl += v2;
  offs[t*4+3] = excl; excl += v3;
  if (t == 1023) offs[4096] = excl;
}

__global__ void fill_csr(const int* __restrict__ row, const int* __restrict__ col,
                         const int* __restrict__ offs, int* __restrict__ cursor,
                         int* __restrict__ src) {
  int e = blockIdx.x * blockDim.x + threadIdx.x;
  if (e < E_EDGES) {
    int c = col[e];
    int p = atomicAdd(&cursor[c], 1);
    src[offs[c] + p] = row[e];
  }
}

// 8 nodes/block, 32 lanes x float4 per node.
__global__ __launch_bounds__(256) void gcn_agg(const float* __restrict__ t,
                                               const float* __restrict__ dinv,
                                               const int* __restrict__ offs,
                                               const int* __restrict__ src,
                                               const float* __restrict__ bias,
                                               float* __restrict__ out) {
  const int node = blockIdx.x * 8 + (threadIdx.x >> 5);
  const int lane = threadIdx.x & 31;
  const float dc = dinv[node];
  float4 a0 = *(const float4*)&t[node * F_DIM + lane * 4];
  a0.x *= dc; a0.y *= dc; a0.z *= dc; a0.w *= dc;
  float4 a1 = make_float4(0.f, 0.f, 0.f, 0.f);
  int e = offs[node], end = offs[node + 1];
  for (; e + 2 <= end; e += 2) {
    int r0 = src[e], r1 = src[e + 1];
    float w0 = dinv[r0], w1 = dinv[r1];
    const float4 v0 = *(const float4*)&t[r0 * F_DIM + lane * 4];
    const float4 v1 = *(const float4*)&t[r1 * F_DIM + lane * 4];
    a0.x = fmaf(w0, v0.x, a0.x); a0.y = fmaf(w0, v0.y, a0.y);
    a0.z = fmaf(w0, v0.z, a0.z); a0.w = fmaf(w0, v0.w, a0.w);
    a1.x = fmaf(w1, v1.x, a1.x); a1.y = fmaf(w1, v1.y, a1.y);
    a1.z = fmaf(w1, v1.z, a1.z); a1.w = fmaf(w1, v1.w, a1.w);
  }
  if (e < end) {
    int r0 = src[e];
    float w0 = dinv[r0];
    const float4 v0 = *(const float4*)&t[r0 * F_DIM + lane * 4];
    a0.x = fmaf(w0, v0.x, a0.x); a0.y = fmaf(w0, v0.y, a0.y);
    a0.z = fmaf(w0, v0.z, a0.z); a0.w = fmaf(w0, v0.w, a0.w);
  }
  a0.x += a1.x; a0.y += a1.y; a0.z += a1.z; a0.w += a1.w;
  const float4 bb = *(const float4*)&bias[lane * 4];
  float4 r;
  r.x = fmaxf(fmaf(a0.x, dc, bb.x), 0.f);
  r.y = fmaxf(fmaf(a0.y, dc, bb.y), 0.f);
  r.z = fmaxf(fmaf(a0.z, dc, bb.z), 0.f);
  r.w = fmaxf(fmaf(a0.w, dc, bb.w), 0.f);
  *(float4*)&out[node * F_DIM + lane * 4] = r;
}

// ---------------- GEMM: TM x 64 tile, BK=32, 256 threads ----------------
// NT=false: B is [K x ldb] row-major; NT=true: B is [Ntot x K] row-major.
// DUAL: C = epi(A@B + A2@B2 + bias + bias2)
template<int TM, bool NT, bool BIAS, bool RELU, bool DUAL>
__global__ __launch_bounds__(256) void gemm2(const float* __restrict__ A,
                                             const float* __restrict__ B,
                                             const float* __restrict__ bias,
                                             const float* __restrict__ A2,
                                             const float* __restrict__ B2,
                                             const float* __restrict__ bias2,
                                             float* __restrict__ C,
                                             int ldb, int ldc) {
  constexpr int K = 128, BK = 32, TN = 64;
  constexpr int RM = TM * TN / 1024;
  constexpr int LDA = 36;
  constexpr int LDB = TN + 4;
  __shared__ float As[BK * LDA];
  __shared__ float Bs[BK * LDB];
  const int tid = threadIdx.x;
  const int tx = tid & 15;
  const int ty = tid >> 4;
  const int row0 = blockIdx.x * TM;
  const int jg0  = blockIdx.y * TN;

  float acc[RM][4];
  #pragma unroll
  for (int r = 0; r < RM; ++r) { acc[r][0]=0.f; acc[r][1]=0.f; acc[r][2]=0.f; acc[r][3]=0.f; }

  for (int pass = 0; pass < (DUAL ? 2 : 1); ++pass) {
    const float* Ap = (DUAL && pass) ? A2 : A;
    const float* Bp = (DUAL && pass) ? B2 : B;
    for (int kc = 0; kc < K; kc += BK) {
      __syncthreads();
      {
        constexpr int NL = TM * BK / 4;
        for (int idx = tid; idx < NL; idx += 256) {
          int m  = idx >> 3;
          int k4 = idx & 7;
          const float4 g = *(const float4*)&Ap[(row0 + m) * K + kc + k4 * 4];
          As[(k4*4+0)*LDA + m] = g.x;
          As[(k4*4+1)*LDA + m] = g.y;
          As[(k4*4+2)*LDA + m] = g.z;
          As[(k4*4+3)*LDA + m] = g.w;
        }
      }
      if constexpr (NT) {
        constexpr int NL = TN * 8;
        for (int idx = tid; idx < NL; idx += 256) {
          int n  = idx >> 3;
          int k4 = idx & 7;
          const float4 g = *(const float4*)&Bp[(jg0 + n) * K + kc + k4 * 4];
          Bs[(k4*4+0)*LDB + n] = g.x;
          Bs[(k4*4+1)*LDB + n] = g.y;
          Bs[(k4*4+2)*LDB + n] = g.z;
          Bs[(k4*4+3)*LDB + n] = g.w;
        }
      } else {
        constexpr int NL = BK * TN / 4;
        for (int idx = tid; idx < NL; idx += 256) {
          int k  = idx >> 4;
          int n4 = idx & 15;
          *(float4*)&Bs[k * LDB + n4 * 4] =
              *(const float4*)&Bp[(kc + k) * ldb + jg0 + n4 * 4];
        }
      }
      __syncthreads();
      #pragma unroll
      for (int k = 0; k < BK; ++k) {
        const float4 bv = *(const float4*)&Bs[k * LDB + tx * 4];
        #pragma unroll
        for (int r = 0; r < RM; ++r) {
          const float a = As[k * LDA + ty * RM + r];
          acc[r][0] = fmaf(a, bv.x, acc[r][0]);
          acc[r][1] = fmaf(a, bv.y, acc[r][1]);
          acc[r][2] = fmaf(a, bv.z, acc[r][2]);
          acc[r][3] = fmaf(a, bv.w, acc[r][3]);
        }
      }
    }
  }

  #pragma unroll
  for (int r = 0; r < RM; ++r) {
    const int gr = row0 + ty * RM + r;
    const int gc = jg0 + tx * 4;
    float4 v = make_float4(acc[r][0], acc[r][1], acc[r][2], acc[r][3]);
    if constexpr (BIAS) {
      const float4 bb = *(const float4*)&bias[gc];
      v.x += bb.x; v.y += bb.y; v.z += bb.z; v.w += bb.w;
    }
    if constexpr (DUAL) {
      const float4 bb = *(const float4*)&bias2[gc];
      v.x += bb.x; v.y += bb.y; v.z += bb.z; v.w += bb.w;
    }
    if constexpr (RELU) {
      v.x = fmaxf(v.x, 0.f); v.y = fmaxf(v.y, 0.f);
      v.z = fmaxf(v.z, 0.f); v.w = fmaxf(v.w, 0.f);
    }
    *(float4*)&C[gr * ldc + gc] = v;
  }
}

// ---------------- per-head max key norm (for bound-softmax) ----------------
__global__ __launch_bounds__(256) void kmax_kernel(const float* __restrict__ qkv,
                                                   float* __restrict__ kmax) {
  const int h = blockIdx.x;
  float mx = 0.f;
  for (int j = threadIdx.x; j < N_NODES; j += 256) {
    const float4* kp = (const float4*)&qkv[j * 384 + 128 + h * HD];
    const float4 k0 = kp[0], k1 = kp[1], k2 = kp[2], k3 = kp[3];
    float n = k0.x*k0.x + k0.y*k0.y + k0.z*k0.z + k0.w*k0.w;
    n += k1.x*k1.x + k1.y*k1.y + k1.z*k1.z + k1.w*k1.w;
    n += k2.x*k2.x + k2.y*k2.y + k2.z*k2.z + k2.w*k2.w;
    n += k3.x*k3.x + k3.y*k3.y + k3.z*k3.z + k3.w*k3.w;
    mx = fmaxf(mx, n);
  }
  #pragma unroll
  for (int mask = 1; mask <= 32; mask <<= 1)
    mx = fmaxf(mx, __shfl_xor(mx, mask, 64));
  __shared__ float red[4];
  if ((threadIdx.x & 63) == 0) red[threadIdx.x >> 6] = mx;
  __syncthreads();
  if (threadIdx.x == 0) {
    float m = fmaxf(fmaxf(red[0], red[1]), fmaxf(red[2], red[3]));
    kmax[h] = sqrtf(m);
  }
}

// ---------------- flash attention v9: bound-softmax, R4 epilogue ------------
// EXACT R4 compile environment (two-phase K-loop, LDS-merge epilogue, 73728 B
// LDS block) + bound-softmax (fixed M_r = ||q'_r||*kmax[h], exp in phase 1,
// no block-max / cor / accumulator rescale; merge is a plain sum since all
// 16 sub-lanes of a row share M_r).
// R4 was the ONLY spill-free attn variant (VGPR=128, WRITE=2MB); every
// shuffle-butterfly / 40960-B-LDS variant (R5-R8) spilled 0.5-1.4 GB to
// scratch regardless of __launch_bounds__. Do not reintroduce either.
__global__ __launch_bounds__(256, 2) void attn_kernel(const float* __restrict__ qkv,
                                                      const float* __restrict__ kmax,
                                                      float* __restrict__ o) {
  constexpr int TQ = 64, TK = 256, LDK = 20;
  // 0..10239: Ks|Vs during main loop; 0..16383: o-partials during merge;
  // 16384..17407: l-partials. Block LDS = 18432 floats = 73728 B (as R4).
  __shared__ float smem[18432];
  float* Ks = smem;
  float* Vs = smem + TK * LDK;
  float* lbuf = smem + 16384;
  const int h   = blockIdx.y;
  const int rg  = threadIdx.x >> 4;     // 16 groups x 4 rows
  const int sub = threadIdx.x & 15;     // key stride 16
  const int row0 = blockIdx.x * TQ + rg * 4;
  const float km = kmax[h];

  float4 q[4][4];
  float M[4];
  #pragma unroll
  for (int r = 0; r < 4; ++r) {
    const float4* qp = (const float4*)&qkv[(row0 + r) * 384 + h * HD];
    float qn = 0.f;
    #pragma unroll
    for (int c = 0; c < 4; ++c) {
      float4 v = qp[c];
      v.x *= 0.25f; v.y *= 0.25f; v.z *= 0.25f; v.w *= 0.25f;
      q[r][c] = v;
      qn += v.x*v.x + v.y*v.y + v.z*v.z + v.w*v.w;
    }
    M[r] = sqrtf(qn) * km;
  }
  float l[4] = {0.f, 0.f, 0.f, 0.f};
  float4 oa[4][4];
  #pragma unroll
  for (int r = 0; r < 4; ++r)
    #pragma unroll
    for (int c = 0; c < 4; ++c) oa[r][c] = make_float4(0.f, 0.f, 0.f, 0.f);

  for (int kt = 0; kt < N_NODES; kt += TK) {
    __syncthreads();
    for (int fi = threadIdx.x; fi < TK * 4; fi += 256) {
      int r = fi >> 2, c4 = fi & 3;
      *(float4*)&Ks[r * LDK + c4 * 4] =
          *(const float4*)&qkv[(kt + r) * 384 + 128 + h * HD + c4 * 4];
      *(float4*)&Vs[r * LDK + c4 * 4] =
          *(const float4*)&qkv[(kt + r) * 384 + 256 + h * HD + c4 * 4];
    }
    __syncthreads();

    for (int j0 = 0; j0 < TK; j0 += 128) {       // thread keys: j0 + kk*16 + sub
      float s[4][8];                              // exp'd scores [row][kk]
      #pragma unroll
      for (int kk = 0; kk < 8; ++kk) {
        const float4* kp = (const float4*)&Ks[(j0 + kk * 16 + sub) * LDK];
        const float4 k0 = kp[0], k1 = kp[1], k2 = kp[2], k3 = kp[3];
        #pragma unroll
        for (int r = 0; r < 4; ++r) {
          float p0 = fmaf(q[r][0].x,k0.x, fmaf(q[r][0].y,k0.y, fmaf(q[r][0].z,k0.z, q[r][0].w*k0.w)));
          float p1 = fmaf(q[r][1].x,k1.x, fmaf(q[r][1].y,k1.y, fmaf(q[r][1].z,k1.z, q[r][1].w*k1.w)));
          float p2 = fmaf(q[r][2].x,k2.x, fmaf(q[r][2].y,k2.y, fmaf(q[r][2].z,k2.z, q[r][2].w*k2.w)));
          float p3 = fmaf(q[r][3].x,k3.x, fmaf(q[r][3].y,k3.y, fmaf(q[r][3].z,k3.z, q[r][3].w*k3.w)));
          s[r][kk] = __expf(((p0 + p1) + (p2 + p3)) - M[r]);
        }
      }
      #pragma unroll
      for (int r = 0; r < 4; ++r) {
        l[r] += ((s[r][0]+s[r][1]) + (s[r][2]+s[r][3])) +
                ((s[r][4]+s[r][5]) + (s[r][6]+s[r][7]));
      }
      #pragma unroll
      for (int kk = 0; kk < 8; ++kk) {
        const float4* vp = (const float4*)&Vs[(j0 + kk * 16 + sub) * LDK];
        const float4 v0 = vp[0], v1 = vp[1], v2 = vp[2], v3 = vp[3];
        #pragma unroll
        for (int r = 0; r < 4; ++r) {
          const float p = s[r][kk];
          oa[r][0].x = fmaf(p, v0.x, oa[r][0].x); oa[r][0].y = fmaf(p, v0.y, oa[r][0].y);
          oa[r][0].z = fmaf(p, v0.z, oa[r][0].z); oa[r][0].w = fmaf(p, v0.w, oa[r][0].w);
          oa[r][1].x = fmaf(p, v1.x, oa[r][1].x); oa[r][1].y = fmaf(p, v1.y, oa[r][1].y);
          oa[r][1].z = fmaf(p, v1.z, oa[r][1].z); oa[r][1].w = fmaf(p, v1.w, oa[r][1].w);
          oa[r][2].x = fmaf(p, v2.x, oa[r][2].x); oa[r][2].y = fmaf(p, v2.y, oa[r][2].y);
          oa[r][2].z = fmaf(p, v2.z, oa[r][2].z); oa[r][2].w = fmaf(p, v2.w, oa[r][2].w);
          oa[r][3].x = fmaf(p, v3.x, oa[r][3].x); oa[r][3].y = fmaf(p, v3.y, oa[r][3].y);
          oa[r][3].z = fmaf(p, v3.z, oa[r][3].z); oa[r][3].w = fmaf(p, v3.w, oa[r][3].w);
        }
      }
    }
  }
  __syncthreads();
  // write 16 partials per row (overwrites Ks/Vs region); plain sums — all
  // sub-lanes of a row used the same M_r.
  #pragma unroll
  for (int r = 0; r < 4; ++r) {
    const int rl = rg * 4 + r;
    lbuf[rl * 16 + sub] = l[r];
    #pragma unroll
    for (int c = 0; c < 4; ++c)
      *(float4*)&smem[(rl * 16 + sub) * HD + c * 4] = oa[r][c];
  }
  __syncthreads();
  // merge: thread = (row, dgroup)
  const int row = threadIdx.x >> 2;
  const int g   = threadIdx.x & 3;
  float L = 0.f;
  float4 acc = make_float4(0.f, 0.f, 0.f, 0.f);
  #pragma unroll
  for (int t16 = 0; t16 < 16; ++t16) {
    L += lbuf[row * 16 + t16];
    const float4 ov = *(const float4*)&smem[(row * 16 + t16) * HD + g * 4];
    acc.x += ov.x; acc.y += ov.y; acc.z += ov.z; acc.w += ov.w;
  }
  const float invL = 1.f / L;
  acc.x *= invL; acc.y *= invL; acc.z *= invL; acc.w *= invL;
  *(float4*)&o[(blockIdx.x * TQ + row) * F_DIM + h * HD + g * 4] = acc;
}

// ---------------- launcher ----------------
extern "C" void kernel_launch(void* const* d_in, const int* in_sizes, int n_in,
                              void* d_out, int out_size, void* d_ws, size_t ws_size,
                              hipStream_t stream) {
  const float* x   = (const float*)d_in[0];
  const int*   ei  = (const int*)  d_in[1];
  const float* W1  = (const float*)d_in[2];
  const float* b1  = (const float*)d_in[3];
  const float* W2  = (const float*)d_in[4];
  const float* b2  = (const float*)d_in[5];
  const float* W3  = (const float*)d_in[6];
  const float* b3  = (const float*)d_in[7];
  const float* ipw = (const float*)d_in[8];
  const float* ipb = (const float*)d_in[9];
  const float* opw = (const float*)d_in[10];
  const float* opb = (const float*)d_in[11];
  const float* pw  = (const float*)d_in[12];
  const float* pb  = (const float*)d_in[13];
  float* out = (float*)d_out;

  int*   deg    = (int*)d_ws;            // 4096
  int*   cursor = deg + 4096;            // 4096
  int*   offs   = cursor + 4096;         // 4100 (4097 used)
  int*   csrc   = offs + 4100;           // 131072
  float* dinv   = (float*)(csrc + E_EDGES);        // 4096
  float* bufA   = dinv + 4096;           // 524288 (t1/t2, then x_tf)
  float* bufB   = bufA + 524288;         // 524288 (h1/h2)
  float* qkv    = bufB + 524288;         // 1572864
  float* obuf   = qkv + 1572864;         // 524288
  float* kmax   = obuf + 524288;         // 8

  const int* rowp = ei;
  const int* colp = ei + E_EDGES;

  hipMemsetAsync(deg, 0, 8192 * sizeof(int), stream);  // deg + cursor
  deg_count<<<E_EDGES / 256, 256, 0, stream>>>(colp, deg);
  scan_kernel<<<1, 1024, 0, stream>>>(deg, offs, dinv);
  fill_csr<<<E_EDGES / 256, 256, 0, stream>>>(rowp, colp, offs, cursor, csrc);

  // GCN branch
  gemm2<32, false, false, false, false><<<dim3(128, 2), 256, 0, stream>>>(
      x, W1, nullptr, nullptr, nullptr, nullptr, bufA, 128, 128);
  gcn_agg<<<N_NODES / 8, 256, 0, stream>>>(bufA, dinv, offs, csrc, b1, bufB);
  gemm2<32, false, false, false, false><<<dim3(128, 2), 256, 0, stream>>>(
      bufB, W2, nullptr, nullptr, nullptr, nullptr, bufA, 128, 128);
  gcn_agg<<<N_NODES / 8, 256, 0, stream>>>(bufA, dinv, offs, csrc, b2, bufB);
  // bufB = h2 (kept for final dual GEMM)

  // transformer branch
  gemm2<32, true, true, false, false><<<dim3(128, 6), 256, 0, stream>>>(
      x, ipw, ipb, nullptr, nullptr, nullptr, qkv, 128, 384);
  kmax_kernel<<<NHEADS, 256, 0, stream>>>(qkv, kmax);
  attn_kernel<<<dim3(64, NHEADS), 256, 0, stream>>>(qkv, kmax, obuf);
  gemm2<32, true, true, false, false><<<dim3(128, 2), 256, 0, stream>>>(
      obuf, opw, opb, nullptr, nullptr, nullptr, bufA, 128, 128);  // bufA = x_tf

  // out = relu(h2@W3 + b3 + x_tf@pw + pb)
  gemm2<16, false, true, true, true><<<dim3(256, 1), 256, 0, stream>>>(
      bufB, W3, b3, bufA, pw, pb, out, 64, C_OUT);
}